// Round 8
// baseline (685.856 us; speedup 1.0000x reference)
//
#include <hip/hip_runtime.h>
#include <hip/hip_bf16.h>

// GAE: 8 stacked GAT layers on N=4096 nodes, dims 512->256->128->64->16->64->128->256->512.
// Outputs (concat in d_out): x_bar[4096*512], h1[4096*256], h2[4096*128], h3[4096*64], h4[4096*16].
//
// Per layer:
//   H = X @ W                      (bf16 MFMA GEMM, fp32 accum; HTt bf16 j-tiled layout written
//                                   directly from the GEMM epilogue via LDS)
//   src = H @ a[:f], tgt = H @ a[f:]; Ev=exp(t-TM), Gv=exp(0.2(t-TM)) with CONSTANT TM=12
//     (factorization exact for any upper bound TM >= max tgt)
//   pass1b: lsum_i = sum_{j in N(i)} max(P_i*Ev_j, Q_i*Gv_j); Av=P/lsum, Bv=Q/lsum (no exp in loop)
//   pass2g: OUT[i,:] = sum_j max(Av_i*Ev_j, Bv_i*Gv_j) * H[j,:]  == softmax(lrelu masked) @ H
// pass2g: 4 waves/block, EACH WAVE OWNS 16 COMPLETE ROWS (64-row i-tile) and the full j-loop:
// no inter-wave combine, no LDS, no barriers, no atomics -> bitwise deterministic, pure ILP.
// All 4 waves read identical B-tile addresses per iter (L1 dedupe). js>1 layers write per-z
// partials reduced deterministically. HTt[j/32][f][j%32] keeps B loads contiguous.
// adj packed to a 2MB bitmask once, reused by all 8 layers.

#define NROWS 4096
#define TMC 12.0f

typedef __attribute__((ext_vector_type(8))) short v8s;
typedef __attribute__((ext_vector_type(4))) float v4f;

__device__ inline unsigned short f2bf(float x) {
  union { float f; unsigned u; } v; v.f = x;
  unsigned r = v.u + 0x7fffu + ((v.u >> 16) & 1u);   // RNE
  return (unsigned short)(r >> 16);
}

// ---- pack adj (int32 0/1) -> bitmask, 64 uint64 words per row ----
__global__ void pack_adj(const int* __restrict__ adj, unsigned long long* __restrict__ bits) {
  int row = blockIdx.x;
  int lane = threadIdx.x & 63, wave = threadIdx.x >> 6;
  for (int w = wave; w < 64; w += 4) {
    unsigned long long m = __ballot(adj[(size_t)row * NROWS + w * 64 + lane] > 0);
    if (lane == 0) bits[row * 64 + w] = m;
  }
}

// ---- batched W transpose: fp32 [K][F] -> bf16 [F][K], all 8 layers in one launch ----
struct WTArgs { const float* src[8]; unsigned short* dst[8]; int K[8]; int F[8]; };
__global__ void transpose_w(WTArgs A) {
  int z = blockIdx.z;
  const float* in = A.src[z];
  unsigned short* out = A.dst[z];
  int R = A.K[z], C = A.F[z];
  __shared__ unsigned short tile[32][33];
  int c0 = blockIdx.x * 32, r0 = blockIdx.y * 32;
  if (c0 >= C || r0 >= R) return;          // block-uniform: safe before barrier
#pragma unroll
  for (int dy = 0; dy < 32; dy += 8) {
    int r = r0 + threadIdx.y + dy, c = c0 + threadIdx.x;
    if (r < R && c < C) tile[threadIdx.y + dy][threadIdx.x] = f2bf(in[(size_t)r * C + c]);
  }
  __syncthreads();
#pragma unroll
  for (int dy = 0; dy < 32; dy += 8) {
    int c = c0 + threadIdx.y + dy, r = r0 + threadIdx.x;
    if (r < R && c < C) out[(size_t)c * R + r] = tile[threadIdx.x][threadIdx.y + dy];
  }
}

// ---- C[4096][Nf] = A_f32[4096][K] x B[K][Nf], B given as BT[Nf][K] bf16 ----
// 2 waves/block, 16 rows each; grid (128, ceil(Nf/64)).
// Epilogue also writes HTt[j/32][f][j%32] bf16 directly (LDS-staged) -> no separate transpose.
__global__ __launch_bounds__(128) void gemm_xw(const float* __restrict__ A,
                                               const unsigned short* __restrict__ BT,
                                               float* __restrict__ C,
                                               unsigned short* __restrict__ HTt,
                                               int K, int Nf) {
  __shared__ unsigned short zone[64 * 36];         // [f_local][j_local], stride 36 vs banks
  int lane = threadIdx.x & 63, wave = threadIdx.x >> 6;
  int quad = lane >> 4, l16 = lane & 15;
  int row0 = blockIdx.x * 32 + wave * 16;
  int col0 = blockIdx.y * 64;
  int nf = Nf - col0; nf = nf > 64 ? 4 : (nf + 15) / 16;
  v4f acc[4] = {{0.f,0.f,0.f,0.f},{0.f,0.f,0.f,0.f},{0.f,0.f,0.f,0.f},{0.f,0.f,0.f,0.f}};
  for (int k0 = 0; k0 < K; k0 += 32) {
    int kk = k0 + quad * 8;
    v8s a = {0,0,0,0,0,0,0,0};
    if (kk < K) {
      float4 f0 = *(const float4*)(A + (size_t)(row0 + l16) * K + kk);
      float4 f1 = *(const float4*)(A + (size_t)(row0 + l16) * K + kk + 4);
      union { v8s s; __hip_bfloat162 h[4]; } ua;
      ua.h[0] = __float22bfloat162_rn(make_float2(f0.x, f0.y));
      ua.h[1] = __float22bfloat162_rn(make_float2(f0.z, f0.w));
      ua.h[2] = __float22bfloat162_rn(make_float2(f1.x, f1.y));
      ua.h[3] = __float22bfloat162_rn(make_float2(f1.z, f1.w));
      a = ua.s;
    }
    for (int t = 0; t < nf; t++) {
      v8s b = {0,0,0,0,0,0,0,0};
      if (kk < K) b = *(const v8s*)(BT + (size_t)(col0 + t * 16 + l16) * K + kk);
      acc[t] = __builtin_amdgcn_mfma_f32_16x16x32_bf16(a, b, acc[t], 0, 0, 0);
    }
  }
  for (int t = 0; t < nf; t++) {
#pragma unroll
    for (int r = 0; r < 4; r++) {
      float v = acc[t][r];
      C[(size_t)(row0 + quad * 4 + r) * Nf + col0 + t * 16 + l16] = v;
      zone[(t * 16 + l16) * 36 + wave * 16 + quad * 4 + r] = f2bf(v);
    }
  }
  __syncthreads();
  // HTt chunk for this block: [row0blk/32][col0..col0+nf*16][0..32): nf*16 f-values x 16 dwords
  unsigned* dst = (unsigned*)(HTt + (size_t)(blockIdx.x) * Nf * 32 + (size_t)col0 * 32);
  const unsigned* zsrc = (const unsigned*)zone;
  int total = nf * 256;                            // dwords (nf*16 f-rows x 32 shorts each)
  for (int idx = threadIdx.x; idx < total; idx += 128) {
    int f = idx >> 4, jp = idx & 15;
    dst[idx] = zsrc[f * 18 + jp];
  }
}

// ---- src/tgt + Ev/Gv: per-row dots of H with a[:f], a[f:]; exp with constant TM ----
__global__ void gemv_srctgt(const float* __restrict__ H, const float* __restrict__ a,
                            float* __restrict__ src, float* __restrict__ Ev,
                            float* __restrict__ Gv, int f) {
  int row = blockIdx.x * 4 + (threadIdx.x >> 6);
  int lane = threadIdx.x & 63;
  float s = 0.f, t = 0.f;
  for (int k = lane; k < f; k += 64) {
    float h = H[(size_t)row * f + k];
    s += h * a[k];
    t += h * a[f + k];
  }
#pragma unroll
  for (int off = 32; off; off >>= 1) { s += __shfl_down(s, off); t += __shfl_down(t, off); }
  if (lane == 0) {
    src[row] = s;
    Ev[row] = __expf(t - TMC);
    Gv[row] = __expf(0.2f * (t - TMC));
  }
}

// ---- pass1b: masked denom via max(P*Ej,Q*Gj); writes Av,Bv directly; no exp in loop ----
__global__ void pass1b(const unsigned long long* __restrict__ bits, const float* __restrict__ src,
                       const float* __restrict__ Ev, const float* __restrict__ Gv,
                       float* __restrict__ Av, float* __restrict__ Bv) {
  int row = blockIdx.x * 4 + (threadIdx.x >> 6);
  int lane = threadIdx.x & 63;
  float sp = src[row] + TMC;                       // s' = s + TM
  float m = sp > 0.f ? sp : 0.2f * sp;             // lrelu(s') >= lrelu(s+t_j) since t_j <= TM
  float P = __expf(sp - m), Q = __expf(0.2f * sp - m);
  const unsigned long long* brow = bits + (size_t)row * 64;
  float lsum = 0.f;
  for (int k = 0; k < 64; k++) {
    unsigned long long w = brow[k];
    float v = fmaxf(P * Ev[k * 64 + lane], Q * Gv[k * 64 + lane]);  // = exp(lrelu(s+t_j)-m)
    lsum += ((w >> lane) & 1ull) ? v : 0.f;
  }
#pragma unroll
  for (int off = 32; off; off >>= 1) lsum += __shfl_xor(lsum, off);
  if (lane == 0) {
    float inv = 1.0f / lsum;
    Av[row] = P * inv;                             // = exp(s' - c), c = m + ln(lsum)
    Bv[row] = Q * inv;
  }
}

// ---- pass2g: OUT = P @ H, P synthesized on the fly (no exp), bf16 MFMA ----
// 4 waves/block; wave w owns rows [i0+w*16, i0+w*16+16) COMPLETELY (full j-loop):
// no combine, no LDS, no barriers. All waves read identical B-tile addresses per iter
// (L1 dedupe). grid (64, fc, js); js>1 -> per-z partials, reduced afterwards.
template<int NF>
__global__ __launch_bounds__(256) void pass2g(const unsigned* __restrict__ adjW,
                                              const float* __restrict__ Av,
                                              const float* __restrict__ Bv,
                                              const float* __restrict__ Ev,
                                              const float* __restrict__ Gv,
                                              const unsigned short* __restrict__ HTt,
                                              float* __restrict__ out, int F, int js) {
  const int W = NF * 16;
  int lane = threadIdx.x & 63, wave = threadIdx.x >> 6;
  int quad = lane >> 4, l16 = lane & 15;
  int i0 = blockIdx.x * 64 + wave * 16;            // this wave's 16 rows
  int fc0 = blockIdx.y * W;
  const size_t F32 = (size_t)F * 32;
  int i = i0 + l16;
  float Ai = Av[i], Bi = Bv[i];
  const unsigned* arow = adjW + (size_t)i * 128;   // 128 adjacency dwords per row
  v4f acc[NF];
#pragma unroll
  for (int t = 0; t < NF; t++) acc[t] = (v4f){0.f, 0.f, 0.f, 0.f};

  int jrange = NROWS / js;
  int jstart = blockIdx.z * jrange;
  for (int j0 = jstart; j0 < jstart + jrange; j0 += 32) {
    int jb = j0 + quad * 8;
    // B-fragments: same addresses for all 4 waves this iter -> L1 reuse
    const unsigned short* bp = HTt + (size_t)(j0 >> 5) * F32 + (size_t)(fc0 + l16) * 32 + quad * 8;
    v8s bfr[NF];
#pragma unroll
    for (int t = 0; t < NF; t++) bfr[t] = *(const v8s*)(bp + t * 512);
    float4 e0 = *(const float4*)(Ev + jb), e1 = *(const float4*)(Ev + jb + 4);
    float4 g0 = *(const float4*)(Gv + jb), g1 = *(const float4*)(Gv + jb + 4);
    float ev[8] = {e0.x, e0.y, e0.z, e0.w, e1.x, e1.y, e1.z, e1.w};
    float gv[8] = {g0.x, g0.y, g0.z, g0.w, g1.x, g1.y, g1.z, g1.w};
    unsigned bb = arow[j0 >> 5] >> (quad * 8);
    float w[8];
#pragma unroll
    for (int jj = 0; jj < 8; jj++) {
      float v = fmaxf(Ai * ev[jj], Bi * gv[jj]);   // exp(lrelu(s+t)-c), factorized
      w[jj] = ((bb >> jj) & 1u) ? v : 0.f;
    }
    union { v8s s; __hip_bfloat162 h[4]; } ua;
#pragma unroll
    for (int p = 0; p < 4; p++)
      ua.h[p] = __float22bfloat162_rn(make_float2(w[2 * p], w[2 * p + 1]));
#pragma unroll
    for (int t = 0; t < NF; t++)
      acc[t] = __builtin_amdgcn_mfma_f32_16x16x32_bf16(ua.s, bfr[t], acc[t], 0, 0, 0);
  }

  // direct store: this wave exclusively owns its 16 rows (C/D: row=quad*4+r, col=l16)
  size_t zoff = (size_t)blockIdx.z * NROWS;        // js==1: 0
#pragma unroll
  for (int t = 0; t < NF; t++)
#pragma unroll
    for (int r = 0; r < 4; r++)
      out[(zoff + i0 + quad * 4 + r) * F + fc0 + t * 16 + l16] = acc[t][r];
}

// ---- deterministic cross-z reduce for js>1 partials ----
__global__ void reduce_js(const float* __restrict__ part, float* __restrict__ out, int n, int js) {
  int i = blockIdx.x * 256 + threadIdx.x;
  if (i < n) {
    float s = part[i];
    for (int z = 1; z < js; z++) s += part[(size_t)z * n + i];
    out[i] = s;
  }
}

static void launch_pass2(int NF, dim3 grid, const unsigned* adjW, const float* Av, const float* Bv,
                         const float* Ev, const float* Gv, const unsigned short* HTt, float* out,
                         int F, int js, hipStream_t stream) {
  switch (NF) {
    case 8: pass2g<8><<<grid, 256, 0, stream>>>(adjW, Av, Bv, Ev, Gv, HTt, out, F, js); break;
    case 4: pass2g<4><<<grid, 256, 0, stream>>>(adjW, Av, Bv, Ev, Gv, HTt, out, F, js); break;
    default: pass2g<1><<<grid, 256, 0, stream>>>(adjW, Av, Bv, Ev, Gv, HTt, out, F, js); break;
  }
}

extern "C" void kernel_launch(void* const* d_in, const int* in_sizes, int n_in,
                              void* d_out, int out_size, void* d_ws, size_t ws_size,
                              hipStream_t stream) {
  static const int fin[8]  = {512, 256, 128, 64, 16, 64, 128, 256};
  static const int fout[8] = {256, 128, 64, 16, 64, 128, 256, 512};

  const float* x = (const float*)d_in[0];
  const int* adj = (const int*)d_in[1];
  char* ws = (char*)d_ws;
  unsigned long long* bits = (unsigned long long*)(ws);                 // 2 MB
  unsigned short* WTall = (unsigned short*)(ws + (2u << 20));           // <1 MB, all layers
  float* H            = (float*)(ws + (6u << 20));                      // 8 MB max
  unsigned short* HTt = (unsigned short*)(ws + (14u << 20));            // 4 MB max
  float* srcv = (float*)(ws + (19u << 20));
  float* Av   = (float*)(ws + (19u << 20) + 49152);
  float* Bv   = (float*)(ws + (19u << 20) + 65536);
  float* Ev   = (float*)(ws + (19u << 20) + 81920);
  float* Gv   = (float*)(ws + (19u << 20) + 98304);
  float* o5   = (float*)(ws + (20u << 20));                             // 1 MB
  float* o6   = (float*)(ws + (21u << 20));                             // 2 MB
  float* o7   = (float*)(ws + (23u << 20));                             // 4 MB
  // js>1 partials (<=4MB) alias H: H's last reader (gemv_srctgt) runs before pass2g.
  float* part = H;

  float* outp = (float*)d_out;
  float* xbar = outp;
  float* h1 = outp + (size_t)NROWS * 512;
  float* h2 = h1 + (size_t)NROWS * 256;
  float* h3 = h2 + (size_t)NROWS * 128;
  float* h4 = h3 + (size_t)NROWS * 64;

  float* louts[8] = {h1, h2, h3, h4, o5, o6, o7, xbar};
  const float* lins[8] = {x, h1, h2, h3, h4, o5, o6, o7};

  unsigned short* WT[8];
  { size_t off = 0;
    for (int t = 0; t < 8; t++) { WT[t] = WTall + off; off += (size_t)fin[t] * fout[t]; } }

  pack_adj<<<dim3(4096), dim3(256), 0, stream>>>(adj, bits);

  WTArgs wa;
  for (int t = 0; t < 8; t++) {
    wa.src[t] = (const float*)d_in[2 + 2 * t];
    wa.dst[t] = WT[t];
    wa.K[t] = fin[t];
    wa.F[t] = fout[t];
  }
  transpose_w<<<dim3(16, 16, 8), dim3(32, 8), 0, stream>>>(wa);

  for (int t = 0; t < 8; t++) {
    int K = fin[t], F = fout[t];
    const float* At = (const float*)d_in[3 + 2 * t];
    const float* Xin = lins[t];
    float* Ot = louts[t];

    // wave-width W = NF*16; grid (64, fc, js) = 256 blocks for every layer
    int NF = F >= 512 ? 8 : (F >= 64 ? 4 : 1);     // 512→8, 256/128/64→4, 16→1
    int fc = F / (16 * NF);                        // 512→4, 256→4, 128→2, 64→1, 16→1
    int js = (F == 128) ? 2 : (F <= 64 ? 4 : 1);

    gemm_xw<<<dim3(128, (F + 63) / 64), dim3(128), 0, stream>>>(Xin, WT[t], H, HTt, K, F);
    gemv_srctgt<<<dim3(1024), dim3(256), 0, stream>>>(H, At, srcv, Ev, Gv, F);
    pass1b<<<dim3(1024), dim3(256), 0, stream>>>(bits, srcv, Ev, Gv, Av, Bv);
    float* p2out = (js > 1) ? part : Ot;
    launch_pass2(NF, dim3(64, fc, js), (const unsigned*)bits, Av, Bv, Ev, Gv, HTt, p2out, F, js,
                 stream);
    if (js > 1)
      reduce_js<<<dim3((NROWS * F + 255) / 256), dim3(256), 0, stream>>>(part, Ot, NROWS * F, js);
  }
}